// Round 2
// baseline (296.235 us; speedup 1.0000x reference)
//
#include <hip/hip_runtime.h>
#include <hip/hip_bf16.h>
#include <float.h>

// Problem constants (B,H,W,D,K) = (16,32,32,256,8192)
#define NROWS 16384
#define DDIM  256
#define KCB   8192
#define ZQ_ELEMS 4194304

// ws layout (~2.2 MB; r0-proven)
#define WS_ESQ_OFF   0                      // float[8192]
#define WS_ZSQ_OFF   32768                  // float[16384]
#define WS_CAND_OFF  98304                  // u32[16384*32] = 2 MB
#define WS_PART_OFF  (98304 + 2097152)      // float[4096]

#define QWINDOW 410   // rescore window: 0.025 in 1/16384 fixed-point quanta

typedef __attribute__((ext_vector_type(8))) short short8;
typedef __attribute__((ext_vector_type(4))) float floatx4;

__device__ __forceinline__ unsigned short bf16_rn(float f) {
    unsigned u = __float_as_uint(f);
    return (unsigned short)((u + 0x7FFFu + ((u >> 16) & 1u)) >> 16);
}

// async global->LDS DMA, 16 B per lane; LDS dest = wave-uniform base + lane*16
__device__ __forceinline__ void gload_lds16(const void* g, void* l) {
    __builtin_amdgcn_global_load_lds(
        (const __attribute__((address_space(1))) void*)(uintptr_t)g,
        (__attribute__((address_space(3))) void*)(unsigned)(uintptr_t)l, 16, 0, 0);
}

// ---------- prep: bf16 convert + numpy-pairwise sumsq (bit-exact, proven r3) ----
__global__ __launch_bounds__(256) void prep_kernel(
    const float* __restrict__ z, const float* __restrict__ cb,
    unsigned short* __restrict__ z16, unsigned short* __restrict__ cb16,
    float* __restrict__ esq, float* __restrict__ zsq) {
#pragma clang fp contract(off)
    int tid = threadIdx.x;
    int rowb = tid >> 2, sub = tid & 3;
    int b = sub >> 1, jq = sub & 1;
    int row = blockIdx.x * 64 + rowb;
    const float* src; unsigned short* dst; float* o;
    if (row < KCB) { src = cb + (size_t)row * DDIM; dst = cb16 + (size_t)row * DDIM; o = esq + row; }
    else { int r = row - KCB; src = z + (size_t)r * DDIM; dst = z16 + (size_t)r * DDIM; o = zsq + r; }
    float r0 = 0.f, r1 = 0.f, r2 = 0.f, r3 = 0.f;
    for (int t = 0; t < 16; ++t) {
        int off = b * 128 + t * 8 + jq * 4;
        float4 v = *(const float4*)(src + off);
        float q0 = v.x * v.x, q1 = v.y * v.y, q2 = v.z * v.z, q3 = v.w * v.w;
        r0 = r0 + q0; r1 = r1 + q1; r2 = r2 + q2; r3 = r3 + q3;
        ushort4 w;
        w.x = bf16_rn(v.x); w.y = bf16_rn(v.y); w.z = bf16_rn(v.z); w.w = bf16_rn(v.w);
        *(ushort4*)(dst + off) = w;
    }
    float s = (r0 + r1) + (r2 + r3);
    s = s + __shfl_xor(s, 1);   // jq pair
    s = s + __shfl_xor(s, 2);   // block pair
    if (sub == 0) *o = s;
}

// ---------- bf16 MFMA filter: block = 64 z-rows x 512 cols ----------
// Same iteration space as the 114.8us baseline (16 (kt,ct)-steps, kt-outer,
// acc[4ct][4f][2nf] persists, A-frags read once per kt). Difference: B is NOT
// staged in LDS. cb16 (4 MB, L2-resident) frags are loaded global->VGPR into a
// 2-slot ring prefetched one step ahead; bytes are identical to the old LDS
// path (frag(nf,ks) = 8 contiguous bf16 at cb16[col][kt*64+ks*32+q*8]), so
// MFMA inputs and accumulation order are bit-exact vs the proven kernel.
// Result: ZERO barriers in the main loop (the old version drained vmcnt(0) +
// s_barrier 16x per block — the dominant stall at MfmaUtil 25%).
__global__ __launch_bounds__(256, 2) void gemm_filter_kernel(
    const unsigned short* __restrict__ z16, const unsigned short* __restrict__ cb16,
    const float* __restrict__ esq, unsigned* __restrict__ cand) {
    __shared__ unsigned short As[64 * 256];     // 32 KB
    __shared__ unsigned st[64][4][2];           // 2 KB cross-wave top-2 merge

    const int tid = threadIdx.x;
    const int w = tid >> 6, lane = tid & 63;
    const int c = lane & 15, q = lane >> 4;
    const int m0 = blockIdx.y * 64;
    const int nbase = blockIdx.x * 512;

    // prologue: stage A tile via DMA (source-addr XOR swizzle, proven layout)
#pragma unroll
    for (int p = 0; p < 8; ++p) {
        int s = (w * 8 + p) * 64 + lane;
        int row = s >> 5, jp = s & 31;
        int j = (jp & 24) | ((jp & 7) ^ (row & 7));
        gload_lds16(z16 + (size_t)(m0 + row) * 256 + j * 8,
                    (char*)As + (w * 8 + p) * 1024);
    }

    // B base pointers (per-lane): col(nf) = nbase + w*32 + nf*16 + c, k-off q*8.
    // step (kt,ct) element offset = ct*32768 + kt*64; ks adds +32 (imm 64B).
    const unsigned short* pB0 = cb16 + (size_t)(nbase + w * 32 + c) * 256 + q * 8;
    const unsigned short* pB1 = pB0 + 16 * 256;

    short8 bb[2][2][2];   // [slot][nf][ks]
    // prologue: step 0 (kt0,ct0) into slot 0 — overlaps A DMA
    bb[0][0][0] = *(const short8*)(pB0);
    bb[0][0][1] = *(const short8*)(pB0 + 32);
    bb[0][1][0] = *(const short8*)(pB1);
    bb[0][1][1] = *(const short8*)(pB1 + 32);
    // advance pointers to step 1 (ct=1)
    pB0 += 32768; pB1 += 32768;

    floatx4 acc[4][4][2];   // [ct][f][nf]
#pragma unroll
    for (int ct = 0; ct < 4; ++ct)
#pragma unroll
        for (int f = 0; f < 4; ++f)
#pragma unroll
            for (int nf = 0; nf < 2; ++nf) acc[ct][f][nf] = (floatx4){0.f, 0.f, 0.f, 0.f};

    short8 af[4][2];   // [f][ks] for current kt

    __syncthreads();   // A tile ready (drains step-0 B prefetch too — once, cheap)

#pragma unroll
    for (int s5 = 0; s5 < 16; ++s5) {
        const int kt = s5 >> 2, ct = s5 & 3, cur = s5 & 1, nxt = cur ^ 1;
        if (s5 < 15) {   // issue next step's 4 B loads at step top (1-step horizon)
            bb[nxt][0][0] = *(const short8*)(pB0);
            bb[nxt][0][1] = *(const short8*)(pB0 + 32);
            bb[nxt][1][0] = *(const short8*)(pB1);
            bb[nxt][1][1] = *(const short8*)(pB1 + 32);
            if (((s5 + 2) & 3) != 0) { pB0 += 32768; pB1 += 32768; }
            else { pB0 += 64 - 3 * 32768; pB1 += 64 - 3 * 32768; }
        }
        if (ct == 0) {   // A-frags for this kt (reused across 4 ct)
#pragma unroll
            for (int f = 0; f < 4; ++f)
#pragma unroll
                for (int ks = 0; ks < 2; ++ks) {
                    int row = f * 16 + c;
                    af[f][ks] = *(const short8*)((const char*)As + row * 512 +
                                 (kt * 8 + (((ks * 4 + q)) ^ (row & 7))) * 16);
                }
        }
#pragma unroll
        for (int f = 0; f < 4; ++f)
#pragma unroll
            for (int nf = 0; nf < 2; ++nf) {
                acc[ct][f][nf] = __builtin_amdgcn_mfma_f32_16x16x32_bf16(
                    af[f][0], bb[cur][nf][0], acc[ct][f][nf], 0, 0, 0);
                acc[ct][f][nf] = __builtin_amdgcn_mfma_f32_16x16x32_bf16(
                    af[f][1], bb[cur][nf][1], acc[ct][f][nf], 0, 0, 0);
            }
    }

    // ---- epilogue (once per block): fixed-point pack + top-2 ----
    float ekf[4][2]; unsigned kb[4][2];
#pragma unroll
    for (int ct = 0; ct < 4; ++ct)
#pragma unroll
        for (int nf = 0; nf < 2; ++nf) {
            int col = nbase + ct * 128 + w * 32 + nf * 16 + c;
            ekf[ct][nf] = (esq[col] + 8.0f) * 16384.0f;   // key+8 in quanta
            kb[ct][nf] = (unsigned)col;
        }
    unsigned b1[4][4], b2[4][4];
#pragma unroll
    for (int f = 0; f < 4; ++f)
#pragma unroll
        for (int r = 0; r < 4; ++r) { b1[f][r] = 0xFFFFFFFFu; b2[f][r] = 0xFFFFFFFFu; }
#pragma unroll
    for (int f = 0; f < 4; ++f)
#pragma unroll
        for (int r = 0; r < 4; ++r)
#pragma unroll
            for (int ct = 0; ct < 4; ++ct)
#pragma unroll
                for (int nf = 0; nf < 2; ++nf) {
                    float fx = fmaf(-32768.0f, acc[ct][f][nf][r], ekf[ct][nf]);
                    unsigned p = ((unsigned)fx << 13) | kb[ct][nf];
                    // top-2 insert: b2 = med3(p,b1,b2); b1 = min(b1,p)  (2 VALU)
                    unsigned nb2;
                    asm("v_med3_u32 %0, %1, %2, %3"
                        : "=v"(nb2) : "v"(p), "v"(b1[f][r]), "v"(b2[f][r]));
                    b2[f][r] = nb2;
                    b1[f][r] = min(b1[f][r], p);
                }
#pragma unroll
    for (int f = 0; f < 4; ++f)
#pragma unroll
        for (int r = 0; r < 4; ++r) {
            unsigned x1 = b1[f][r], x2 = b2[f][r];
#pragma unroll
            for (int sft = 1; sft < 16; sft <<= 1) {
                unsigned o1 = __shfl_xor(x1, sft);
                unsigned o2 = __shfl_xor(x2, sft);
                unsigned mx = max(x1, o1);
                x1 = min(x1, o1);
                x2 = min(min(mx, x2), o2);
            }
            if (c == 0) {
                st[f * 16 + q * 4 + r][w][0] = x1;
                st[f * 16 + q * 4 + r][w][1] = x2;
            }
        }
    __syncthreads();
    if (tid < 64) {
        unsigned a1 = st[tid][0][0], a2 = st[tid][0][1];
#pragma unroll
        for (int ww = 1; ww < 4; ++ww) {
            unsigned p1 = st[tid][ww][0], p2 = st[tid][ww][1];
            unsigned mx = max(a1, p1);
            a1 = min(a1, p1);
            a2 = min(min(mx, a2), p2);
        }
        cand[(size_t)(m0 + tid) * 32 + blockIdx.x * 2 + 0] = a1;
        cand[(size_t)(m0 + tid) * 32 + blockIdx.x * 2 + 1] = a2;
    }
}

// ---------- resolve (numpy-replica fp32 rescore, proven r3/r4) + gather ------
__global__ __launch_bounds__(256) void resolve_gather_kernel(
    const float* __restrict__ z, const float* __restrict__ cb,
    const float* __restrict__ zsq, const float* __restrict__ esq,
    const unsigned* __restrict__ cand, float* __restrict__ out,
    float* __restrict__ partials) {
#pragma clang fp contract(off)
    __shared__ float wls[4];
    int w = threadIdx.x >> 6, l = threadIdx.x & 63;
    int row = blockIdx.x * 4 + w;
    unsigned p = (l < 32) ? cand[(size_t)row * 32 + l] : 0xFFFFFFFFu;
    unsigned m = p;
#pragma unroll
    for (int s = 32; s; s >>= 1) m = min(m, __shfl_xor(m, s));
    bool active = (l < 32) && ((p >> 13) <= (m >> 13) + QWINDOW);
    float dref = FLT_MAX; int k = 0x7FFFFFFF;
    if (active) {
        k = (int)(p & 8191u);
        const float* zr = z + (size_t)row * DDIM;
        const float* er = cb + (size_t)k * DDIM;
        float cacc = 0.f;
        for (int d = 0; d < DDIM; ++d)
            cacc = fmaf(zr[d], er[d], cacc);   // BLAS-style sequential-K fma chain
        float s1 = zsq[row] + esq[k];          // numpy: z_sq + e_sq (fp32 round)
        float two = 2.0f * cacc;               // exact
        dref = s1 - two;                       // single fp32 round
    }
#pragma unroll
    for (int s = 32; s; s >>= 1) {
        float od = __shfl_xor(dref, s);
        int ok = __shfl_xor(k, s);
        if (od < dref || (od == dref && ok < k)) { dref = od; k = ok; }
    }
    if (l == 0) out[ZQ_ELEMS + row] = (float)k;
    float ls = 0.f;
#pragma unroll
    for (int t = 0; t < 4; ++t) {
        int d = l + t * 64;
        float e = cb[(size_t)k * DDIM + d];
        float zv = z[(size_t)row * DDIM + d];
        out[(size_t)row * DDIM + d] = zv + (e - zv);  // z_q_st == z_q numerically
        float df = zv - e;
        ls = fmaf(df, df, ls);
    }
#pragma unroll
    for (int s = 32; s; s >>= 1) ls += __shfl_xor(ls, s);
    if (l == 0) wls[w] = ls;
    __syncthreads();
    if (threadIdx.x == 0)
        partials[blockIdx.x] = (wls[0] + wls[1]) + (wls[2] + wls[3]);
}

__global__ __launch_bounds__(256) void final_kernel(const float* __restrict__ partials,
                                                    float* __restrict__ out) {
    __shared__ double wd[4];
    int w = threadIdx.x >> 6, l = threadIdx.x & 63;
    double s = 0.0;
#pragma unroll
    for (int j = 0; j < 16; ++j) s += (double)partials[threadIdx.x + j * 256];
#pragma unroll
    for (int sh = 32; sh; sh >>= 1) s += __shfl_xor(s, sh);
    if (l == 0) wd[w] = s;
    __syncthreads();
    if (threadIdx.x == 0)
        out[ZQ_ELEMS + NROWS] =
            (float)(1.25 * ((wd[0] + wd[1]) + (wd[2] + wd[3])) / (double)ZQ_ELEMS);
}

extern "C" void kernel_launch(void* const* d_in, const int* in_sizes, int n_in,
                              void* d_out, int out_size, void* d_ws, size_t ws_size,
                              hipStream_t stream) {
    const float* z = (const float*)d_in[0];
    const float* cb = (const float*)d_in[1];
    float* out = (float*)d_out;
    char* ws = (char*)d_ws;
    float* esq = (float*)(ws + WS_ESQ_OFF);
    float* zsq = (float*)(ws + WS_ZSQ_OFF);
    unsigned* cand = (unsigned*)(ws + WS_CAND_OFF);
    float* partials = (float*)(ws + WS_PART_OFF);
    // bf16 scratch inside d_out (12 MB < 16.8 MB); overwritten by outputs later
    unsigned short* z16 = (unsigned short*)d_out;
    unsigned short* cb16 = z16 + (size_t)NROWS * DDIM;

    prep_kernel<<<dim3((KCB + NROWS) / 64), 256, 0, stream>>>(z, cb, z16, cb16, esq, zsq);
    gemm_filter_kernel<<<dim3(16, NROWS / 64), 256, 0, stream>>>(z16, cb16, esq, cand);
    resolve_gather_kernel<<<dim3(NROWS / 4), 256, 0, stream>>>(z, cb, zsq, esq, cand, out, partials);
    final_kernel<<<1, 256, 0, stream>>>(partials, out);
}

// Round 4
// 251.908 us; speedup vs baseline: 1.1760x; 1.1760x over previous
//
#include <hip/hip_runtime.h>
#include <hip/hip_bf16.h>
#include <float.h>

// Problem constants (B,H,W,D,K) = (16,32,32,256,8192)
#define NROWS 16384
#define DDIM  256
#define KCB   8192
#define ZQ_ELEMS 4194304

// ws layout (~2.2 MB; r0-proven)
#define WS_ESQ_OFF   0                      // float[8192]
#define WS_ZSQ_OFF   32768                  // float[16384]
#define WS_CAND_OFF  98304                  // u32[16384*32] = 2 MB
#define WS_PART_OFF  (98304 + 2097152)      // float[4096]

#define QWINDOW 410   // rescore window: 0.025 in 1/16384 fixed-point quanta

typedef __attribute__((ext_vector_type(8))) short short8;
typedef __attribute__((ext_vector_type(4))) float floatx4;

__device__ __forceinline__ unsigned short bf16_rn(float f) {
    unsigned u = __float_as_uint(f);
    return (unsigned short)((u + 0x7FFFu + ((u >> 16) & 1u)) >> 16);
}

// async global->LDS DMA, 16 B per lane; LDS dest = wave-uniform base + lane*16
__device__ __forceinline__ void gload_lds16(const void* g, void* l) {
    __builtin_amdgcn_global_load_lds(
        (const __attribute__((address_space(1))) void*)(uintptr_t)g,
        (__attribute__((address_space(3))) void*)(unsigned)(uintptr_t)l, 16, 0, 0);
}

// ---------- prep: bf16 convert + numpy-pairwise sumsq (bit-exact, proven r3) ----
__global__ __launch_bounds__(256) void prep_kernel(
    const float* __restrict__ z, const float* __restrict__ cb,
    unsigned short* __restrict__ z16, unsigned short* __restrict__ cb16,
    float* __restrict__ esq, float* __restrict__ zsq) {
#pragma clang fp contract(off)
    int tid = threadIdx.x;
    int rowb = tid >> 2, sub = tid & 3;
    int b = sub >> 1, jq = sub & 1;
    int row = blockIdx.x * 64 + rowb;
    const float* src; unsigned short* dst; float* o;
    if (row < KCB) { src = cb + (size_t)row * DDIM; dst = cb16 + (size_t)row * DDIM; o = esq + row; }
    else { int r = row - KCB; src = z + (size_t)r * DDIM; dst = z16 + (size_t)r * DDIM; o = zsq + r; }
    float r0 = 0.f, r1 = 0.f, r2 = 0.f, r3 = 0.f;
    for (int t = 0; t < 16; ++t) {
        int off = b * 128 + t * 8 + jq * 4;
        float4 v = *(const float4*)(src + off);
        float q0 = v.x * v.x, q1 = v.y * v.y, q2 = v.z * v.z, q3 = v.w * v.w;
        r0 = r0 + q0; r1 = r1 + q1; r2 = r2 + q2; r3 = r3 + q3;
        ushort4 w;
        w.x = bf16_rn(v.x); w.y = bf16_rn(v.y); w.z = bf16_rn(v.z); w.w = bf16_rn(v.w);
        *(ushort4*)(dst + off) = w;
    }
    float s = (r0 + r1) + (r2 + r3);
    s = s + __shfl_xor(s, 1);   // jq pair
    s = s + __shfl_xor(s, 2);   // block pair
    if (sub == 0) *o = s;
}

// ---------- bf16 MFMA filter: block = 64 z-rows x 512 cols ----------
// Identical iteration space / MFMA inputs / epilogue to the 114.8us baseline
// (16 (kt,ct)-steps, kt-outer, acc[4ct][4f][2nf], B chunks DMA'd to LDS).
// KEY FIX vs baseline: the B chunk buffers are WAVE-PRIVATE (wave w stages
// cols [w*32,w*32+32) and reads exactly those back), so the per-step
// __syncthreads() (which drained vmcnt(0) and serialized DMA behind MFMA)
// is replaced by per-wave COUNTED s_waitcnt vmcnt(N): 2 chunks in flight,
// zero main-loop barriers. One __syncthreads() in the prologue (drains ALL
// prologue DMAs — correctness independent of DMA issue order; once, cheap).
__global__ __launch_bounds__(256, 2) void gemm_filter_kernel(
    const unsigned short* __restrict__ z16, const unsigned short* __restrict__ cb16,
    const float* __restrict__ esq, unsigned* __restrict__ cand) {
    __shared__ unsigned short As[64 * 256];     // 32 KB
    __shared__ unsigned short Bs[2][128 * 64];  // 2 x 16 KB
    __shared__ unsigned st[64][4][2];           // 2 KB cross-wave top-2 merge

    const int tid = threadIdx.x;
    const int w = tid >> 6, lane = tid & 63;
    const int c = lane & 15, q = lane >> 4;
    const int m0 = blockIdx.y * 64;
    const int nbase = blockIdx.x * 512;

    // ---- prologue: A tile (8 DMA loads) + B chunks 0,1 (4 loads each) ----
#pragma unroll
    for (int p = 0; p < 8; ++p) {
        int s = (w * 8 + p) * 64 + lane;
        int row = s >> 5, jp = s & 31;
        int j = (jp & 24) | ((jp & 7) ^ (row & 7));   // source-addr XOR swizzle
        gload_lds16(z16 + (size_t)(m0 + row) * 256 + j * 8,
                    (char*)As + (w * 8 + p) * 1024);
    }
#pragma unroll
    for (int n = 0; n < 2; ++n)
#pragma unroll
        for (int p = 0; p < 4; ++p) {
            int s = (w * 4 + p) * 64 + lane;
            int col = s >> 3, jp = s & 7;
            int j = jp ^ (col & 7);
            gload_lds16(cb16 + (size_t)(nbase + n * 128 + col) * 256 + j * 8,
                        (char*)Bs[n] + (w * 4 + p) * 1024);
        }

    floatx4 acc[4][4][2];   // [ct][f][nf]
#pragma unroll
    for (int ct = 0; ct < 4; ++ct)
#pragma unroll
        for (int f = 0; f < 4; ++f)
#pragma unroll
            for (int nf = 0; nf < 2; ++nf) acc[ct][f][nf] = (floatx4){0.f, 0.f, 0.f, 0.f};

    short8 af[4][2];   // [f][ks] for current kt

    __syncthreads();   // drains ALL prologue DMAs (A+B0+B1); order-independent

#pragma unroll
    for (int s5 = 0; s5 < 16; ++s5) {
        const int kt = s5 >> 2, ct = s5 & 3, cur = s5 & 1;
        // chunk s5's 4 loads complete; chunk s5+1's 4 may stay in flight
        if (s5 < 15) { asm volatile("s_waitcnt vmcnt(4)" ::: "memory"); }
        else         { asm volatile("s_waitcnt vmcnt(0)" ::: "memory"); }
        if (ct == 0) {   // A-frags for this kt (reused across 4 ct)
#pragma unroll
            for (int f = 0; f < 4; ++f)
#pragma unroll
                for (int ks = 0; ks < 2; ++ks) {
                    int row = f * 16 + c;
                    af[f][ks] = *(const short8*)((const char*)As + row * 512 +
                                 (kt * 8 + (((ks * 4 + q)) ^ (row & 7))) * 16);
                }
        }
        short8 bf[2][2];
#pragma unroll
        for (int nf = 0; nf < 2; ++nf)
#pragma unroll
            for (int ks = 0; ks < 2; ++ks) {
                int col = w * 32 + nf * 16 + c;
                bf[nf][ks] = *(const short8*)((const char*)Bs[cur] + col * 128 +
                              (((ks * 4 + q) ^ (col & 7))) * 16);
            }
        // frags now in VGPRs; drain LDS reads so the DMA below may overwrite Bs[cur]
        asm volatile("s_waitcnt lgkmcnt(0)" ::: "memory");
        if (s5 < 14) {   // issue chunk s5+2 into the buffer just consumed (wave-private)
            const int n2 = s5 + 2, nkt = n2 >> 2, nct = n2 & 3;
#pragma unroll
            for (int p = 0; p < 4; ++p) {
                int s = (w * 4 + p) * 64 + lane;
                int col = s >> 3, jp = s & 7;
                int j = jp ^ (col & 7);
                gload_lds16(cb16 + (size_t)(nbase + nct * 128 + col) * 256 + nkt * 64 + j * 8,
                            (char*)Bs[cur] + (w * 4 + p) * 1024);
            }
        }
#pragma unroll
        for (int f = 0; f < 4; ++f)
#pragma unroll
            for (int nf = 0; nf < 2; ++nf) {
                acc[ct][f][nf] = __builtin_amdgcn_mfma_f32_16x16x32_bf16(
                    af[f][0], bf[nf][0], acc[ct][f][nf], 0, 0, 0);
                acc[ct][f][nf] = __builtin_amdgcn_mfma_f32_16x16x32_bf16(
                    af[f][1], bf[nf][1], acc[ct][f][nf], 0, 0, 0);
            }
    }
    __builtin_amdgcn_sched_barrier(0);   // keep epilogue vmem out of the counted window

    // ---- epilogue (once per block): fixed-point pack + top-2 ----
    float ekf[4][2]; unsigned kb[4][2];
#pragma unroll
    for (int ct = 0; ct < 4; ++ct)
#pragma unroll
        for (int nf = 0; nf < 2; ++nf) {
            int col = nbase + ct * 128 + w * 32 + nf * 16 + c;
            ekf[ct][nf] = (esq[col] + 8.0f) * 16384.0f;   // key+8 in quanta
            kb[ct][nf] = (unsigned)col;
        }
    unsigned b1[4][4], b2[4][4];
#pragma unroll
    for (int f = 0; f < 4; ++f)
#pragma unroll
        for (int r = 0; r < 4; ++r) { b1[f][r] = 0xFFFFFFFFu; b2[f][r] = 0xFFFFFFFFu; }
#pragma unroll
    for (int f = 0; f < 4; ++f)
#pragma unroll
        for (int r = 0; r < 4; ++r)
#pragma unroll
            for (int ct = 0; ct < 4; ++ct)
#pragma unroll
                for (int nf = 0; nf < 2; ++nf) {
                    float fx = fmaf(-32768.0f, acc[ct][f][nf][r], ekf[ct][nf]);
                    unsigned p = ((unsigned)fx << 13) | kb[ct][nf];
                    // top-2 insert: b2 = med3(p,b1,b2); b1 = min(b1,p)
                    unsigned nb2;
                    asm("v_med3_u32 %0, %1, %2, %3"
                        : "=v"(nb2) : "v"(p), "v"(b1[f][r]), "v"(b2[f][r]));
                    b2[f][r] = nb2;
                    b1[f][r] = min(b1[f][r], p);
                }
#pragma unroll
    for (int f = 0; f < 4; ++f)
#pragma unroll
        for (int r = 0; r < 4; ++r) {
            unsigned x1 = b1[f][r], x2 = b2[f][r];
#pragma unroll
            for (int sft = 1; sft < 16; sft <<= 1) {
                unsigned o1 = __shfl_xor(x1, sft);
                unsigned o2 = __shfl_xor(x2, sft);
                unsigned mx = max(x1, o1);
                x1 = min(x1, o1);
                x2 = min(min(mx, x2), o2);
            }
            if (c == 0) {
                st[f * 16 + q * 4 + r][w][0] = x1;
                st[f * 16 + q * 4 + r][w][1] = x2;
            }
        }
    __syncthreads();
    if (tid < 64) {
        unsigned a1 = st[tid][0][0], a2 = st[tid][0][1];
#pragma unroll
        for (int ww = 1; ww < 4; ++ww) {
            unsigned p1 = st[tid][ww][0], p2 = st[tid][ww][1];
            unsigned mx = max(a1, p1);
            a1 = min(a1, p1);
            a2 = min(min(mx, a2), p2);
        }
        cand[(size_t)(m0 + tid) * 32 + blockIdx.x * 2 + 0] = a1;
        cand[(size_t)(m0 + tid) * 32 + blockIdx.x * 2 + 1] = a2;
    }
}

// ---------- resolve (numpy-replica fp32 rescore, proven r3/r4) + gather ------
__global__ __launch_bounds__(256) void resolve_gather_kernel(
    const float* __restrict__ z, const float* __restrict__ cb,
    const float* __restrict__ zsq, const float* __restrict__ esq,
    const unsigned* __restrict__ cand, float* __restrict__ out,
    float* __restrict__ partials) {
#pragma clang fp contract(off)
    __shared__ float wls[4];
    int w = threadIdx.x >> 6, l = threadIdx.x & 63;
    int row = blockIdx.x * 4 + w;
    unsigned p = (l < 32) ? cand[(size_t)row * 32 + l] : 0xFFFFFFFFu;
    unsigned m = p;
#pragma unroll
    for (int s = 32; s; s >>= 1) m = min(m, __shfl_xor(m, s));
    bool active = (l < 32) && ((p >> 13) <= (m >> 13) + QWINDOW);
    float dref = FLT_MAX; int k = 0x7FFFFFFF;
    if (active) {
        k = (int)(p & 8191u);
        const float* zr = z + (size_t)row * DDIM;
        const float* er = cb + (size_t)k * DDIM;
        float cacc = 0.f;
        for (int d = 0; d < DDIM; ++d)
            cacc = fmaf(zr[d], er[d], cacc);   // BLAS-style sequential-K fma chain
        float s1 = zsq[row] + esq[k];          // numpy: z_sq + e_sq (fp32 round)
        float two = 2.0f * cacc;               // exact
        dref = s1 - two;                       // single fp32 round
    }
#pragma unroll
    for (int s = 32; s; s >>= 1) {
        float od = __shfl_xor(dref, s);
        int ok = __shfl_xor(k, s);
        if (od < dref || (od == dref && ok < k)) { dref = od; k = ok; }
    }
    if (l == 0) out[ZQ_ELEMS + row] = (float)k;
    float ls = 0.f;
#pragma unroll
    for (int t = 0; t < 4; ++t) {
        int d = l + t * 64;
        float e = cb[(size_t)k * DDIM + d];
        float zv = z[(size_t)row * DDIM + d];
        out[(size_t)row * DDIM + d] = zv + (e - zv);  // z_q_st == z_q numerically
        float df = zv - e;
        ls = fmaf(df, df, ls);
    }
#pragma unroll
    for (int s = 32; s; s >>= 1) ls += __shfl_xor(ls, s);
    if (l == 0) wls[w] = ls;
    __syncthreads();
    if (threadIdx.x == 0)
        partials[blockIdx.x] = (wls[0] + wls[1]) + (wls[2] + wls[3]);
}

__global__ __launch_bounds__(256) void final_kernel(const float* __restrict__ partials,
                                                    float* __restrict__ out) {
    __shared__ double wd[4];
    int w = threadIdx.x >> 6, l = threadIdx.x & 63;
    double s = 0.0;
#pragma unroll
    for (int j = 0; j < 16; ++j) s += (double)partials[threadIdx.x + j * 256];
#pragma unroll
    for (int sh = 32; sh; sh >>= 1) s += __shfl_xor(s, sh);
    if (l == 0) wd[w] = s;
    __syncthreads();
    if (threadIdx.x == 0)
        out[ZQ_ELEMS + NROWS] =
            (float)(1.25 * ((wd[0] + wd[1]) + (wd[2] + wd[3])) / (double)ZQ_ELEMS);
}

extern "C" void kernel_launch(void* const* d_in, const int* in_sizes, int n_in,
                              void* d_out, int out_size, void* d_ws, size_t ws_size,
                              hipStream_t stream) {
    const float* z = (const float*)d_in[0];
    const float* cb = (const float*)d_in[1];
    float* out = (float*)d_out;
    char* ws = (char*)d_ws;
    float* esq = (float*)(ws + WS_ESQ_OFF);
    float* zsq = (float*)(ws + WS_ZSQ_OFF);
    unsigned* cand = (unsigned*)(ws + WS_CAND_OFF);
    float* partials = (float*)(ws + WS_PART_OFF);
    // bf16 scratch inside d_out (12 MB < 16.8 MB); overwritten by outputs later
    unsigned short* z16 = (unsigned short*)d_out;
    unsigned short* cb16 = z16 + (size_t)NROWS * DDIM;

    prep_kernel<<<dim3((KCB + NROWS) / 64), 256, 0, stream>>>(z, cb, z16, cb16, esq, zsq);
    gemm_filter_kernel<<<dim3(16, NROWS / 64), 256, 0, stream>>>(z16, cb16, esq, cand);
    resolve_gather_kernel<<<dim3(NROWS / 4), 256, 0, stream>>>(z, cb, zsq, esq, cand, out, partials);
    final_kernel<<<1, 256, 0, stream>>>(partials, out);
}

// Round 5
// 245.176 us; speedup vs baseline: 1.2083x; 1.0275x over previous
//
#include <hip/hip_runtime.h>
#include <hip/hip_bf16.h>
#include <float.h>

// Problem constants (B,H,W,D,K) = (16,32,32,256,8192)
#define NROWS 16384
#define DDIM  256
#define KCB   8192
#define ZQ_ELEMS 4194304

// ws layout (~2.2 MB; r0-proven)
#define WS_ESQ_OFF   0                      // float[8192]
#define WS_ZSQ_OFF   32768                  // float[16384]
#define WS_CAND_OFF  98304                  // u32[16384*32] = 2 MB
#define WS_PART_OFF  (98304 + 2097152)      // float[4096]

#define QWINDOW 410   // rescore window: 0.025 in 1/16384 fixed-point quanta

typedef __attribute__((ext_vector_type(8))) short short8;
typedef __attribute__((ext_vector_type(4))) float floatx4;

__device__ __forceinline__ unsigned short bf16_rn(float f) {
    unsigned u = __float_as_uint(f);
    return (unsigned short)((u + 0x7FFFu + ((u >> 16) & 1u)) >> 16);
}

// async global->LDS DMA, 16 B per lane; LDS dest = wave-uniform base + lane*16
__device__ __forceinline__ void gload_lds16(const void* g, void* l) {
    __builtin_amdgcn_global_load_lds(
        (const __attribute__((address_space(1))) void*)(uintptr_t)g,
        (__attribute__((address_space(3))) void*)(unsigned)(uintptr_t)l, 16, 0, 0);
}

// ---------- prep: bf16 convert + numpy-pairwise sumsq (bit-exact, proven r3) ----
__global__ __launch_bounds__(256) void prep_kernel(
    const float* __restrict__ z, const float* __restrict__ cb,
    unsigned short* __restrict__ z16, unsigned short* __restrict__ cb16,
    float* __restrict__ esq, float* __restrict__ zsq) {
#pragma clang fp contract(off)
    int tid = threadIdx.x;
    int rowb = tid >> 2, sub = tid & 3;
    int b = sub >> 1, jq = sub & 1;
    int row = blockIdx.x * 64 + rowb;
    const float* src; unsigned short* dst; float* o;
    if (row < KCB) { src = cb + (size_t)row * DDIM; dst = cb16 + (size_t)row * DDIM; o = esq + row; }
    else { int r = row - KCB; src = z + (size_t)r * DDIM; dst = z16 + (size_t)r * DDIM; o = zsq + r; }
    float r0 = 0.f, r1 = 0.f, r2 = 0.f, r3 = 0.f;
#pragma unroll   // scheduling only: 16 independent float4 loads pipelined; fp order unchanged
    for (int t = 0; t < 16; ++t) {
        int off = b * 128 + t * 8 + jq * 4;
        float4 v = *(const float4*)(src + off);
        float q0 = v.x * v.x, q1 = v.y * v.y, q2 = v.z * v.z, q3 = v.w * v.w;
        r0 = r0 + q0; r1 = r1 + q1; r2 = r2 + q2; r3 = r3 + q3;
        ushort4 w;
        w.x = bf16_rn(v.x); w.y = bf16_rn(v.y); w.z = bf16_rn(v.z); w.w = bf16_rn(v.w);
        *(ushort4*)(dst + off) = w;
    }
    float s = (r0 + r1) + (r2 + r3);
    s = s + __shfl_xor(s, 1);   // jq pair
    s = s + __shfl_xor(s, 2);   // block pair
    if (sub == 0) *o = s;
}

// ---------- bf16 MFMA filter: block = 64 z-rows x 512 cols ----------
// Same iteration space / MFMA inputs / epilogue as the 114.8us baseline.
// R4 lesson: replacing per-step barriers with counted vmcnt changed NOTHING ->
// the stall is the INTRA-WAVE serial step (ds_read -> lgkmcnt(0) -> MFMA
// exposes full LDS latency every step at only ~2 waves/SIMD).
// THIS version software-pipelines operand fetch one step ahead in registers:
//   step s: [lgkm(0): bf[s]/af ready] [DMA chunk s+2 -> Bs[s&1]]
//           [vmcnt(4): chunk s+1 landed] [ds_read bf[s+1] (+af[kt+1] at ct==3)]
//           [sched_barrier] [16 MFMA on bf[s] - register-only, no waits]
// Prefetch latency hides under the MFMA cluster. Zero main-loop barriers
// (B buffers wave-private, R4-proven). Hazards: Bs[s&1] reads drained at
// step-top lgkm(0) before overwrite; vmcnt(4) before reading chunk s+1.
__global__ __launch_bounds__(256, 2) void gemm_filter_kernel(
    const unsigned short* __restrict__ z16, const unsigned short* __restrict__ cb16,
    const float* __restrict__ esq, unsigned* __restrict__ cand) {
    __shared__ unsigned short As[64 * 256];     // 32 KB
    __shared__ unsigned short Bs[2][128 * 64];  // 2 x 16 KB
    __shared__ unsigned st[64][4][2];           // 2 KB cross-wave top-2 merge

    const int tid = threadIdx.x;
    const int w = tid >> 6, lane = tid & 63;
    const int c = lane & 15, q = lane >> 4;
    const int m0 = blockIdx.y * 64;
    const int nbase = blockIdx.x * 512;

    // ---- prologue: A tile (8 DMA loads) + B chunks 0,1 (4 loads each) ----
#pragma unroll
    for (int p = 0; p < 8; ++p) {
        int s = (w * 8 + p) * 64 + lane;
        int row = s >> 5, jp = s & 31;
        int j = (jp & 24) | ((jp & 7) ^ (row & 7));   // source-addr XOR swizzle
        gload_lds16(z16 + (size_t)(m0 + row) * 256 + j * 8,
                    (char*)As + (w * 8 + p) * 1024);
    }
#pragma unroll
    for (int n = 0; n < 2; ++n)
#pragma unroll
        for (int p = 0; p < 4; ++p) {
            int s = (w * 4 + p) * 64 + lane;
            int col = s >> 3, jp = s & 7;
            int j = jp ^ (col & 7);
            gload_lds16(cb16 + (size_t)(nbase + n * 128 + col) * 256 + j * 8,
                        (char*)Bs[n] + (w * 4 + p) * 1024);
        }

    floatx4 acc[4][4][2];   // [ct][f][nf]
#pragma unroll
    for (int ct = 0; ct < 4; ++ct)
#pragma unroll
        for (int f = 0; f < 4; ++f)
#pragma unroll
            for (int nf = 0; nf < 2; ++nf) acc[ct][f][nf] = (floatx4){0.f, 0.f, 0.f, 0.f};

    short8 afb[2][4][2];   // [kt&1][f][ks] — current / next-kt A-frags
    short8 bfb[2][2][2];   // [s&1][nf][ks] — chunk s lives in slot s&1

    __syncthreads();   // drains ALL prologue DMAs (A+B0+B1); order-independent

    // prefetch step 0 operands (drained at step-0 top)
#pragma unroll
    for (int f = 0; f < 4; ++f)
#pragma unroll
        for (int ks = 0; ks < 2; ++ks) {
            int row = f * 16 + c;
            afb[0][f][ks] = *(const short8*)((const char*)As + row * 512 +
                             ((((ks * 4 + q)) ^ (row & 7))) * 16);
        }
#pragma unroll
    for (int nf = 0; nf < 2; ++nf)
#pragma unroll
        for (int ks = 0; ks < 2; ++ks) {
            int col = w * 32 + nf * 16 + c;
            bfb[0][nf][ks] = *(const short8*)((const char*)Bs[0] + col * 128 +
                              (((ks * 4 + q) ^ (col & 7))) * 16);
        }

#pragma unroll
    for (int s5 = 0; s5 < 16; ++s5) {
        const int kt = s5 >> 2, ct = s5 & 3, cb_ = s5 & 1, nb_ = (s5 + 1) & 1;
        // bf[s5] (+ af prefetched earlier) landed; Bs[cb_] reads complete
        asm volatile("s_waitcnt lgkmcnt(0)" ::: "memory");
        if (s5 < 14) {   // issue chunk s5+2 into the buffer just freed (wave-private)
            const int n2 = s5 + 2, nkt = n2 >> 2, nct = n2 & 3;
#pragma unroll
            for (int p = 0; p < 4; ++p) {
                int s = (w * 4 + p) * 64 + lane;
                int col = s >> 3, jp = s & 7;
                int j = jp ^ (col & 7);
                gload_lds16(cb16 + (size_t)(nbase + nct * 128 + col) * 256 + nkt * 64 + j * 8,
                            (char*)Bs[cb_] + (w * 4 + p) * 1024);
            }
        }
        if (s5 < 15) {
            // chunk s5+1 landed (s5+2 may stay in flight)
            if (s5 == 14) { asm volatile("s_waitcnt vmcnt(0)" ::: "memory"); }
            else          { asm volatile("s_waitcnt vmcnt(4)" ::: "memory"); }
            // prefetch bf[s5+1] — latency hides under this step's MFMA cluster
#pragma unroll
            for (int nf = 0; nf < 2; ++nf)
#pragma unroll
                for (int ks = 0; ks < 2; ++ks) {
                    int col = w * 32 + nf * 16 + c;
                    bfb[nb_][nf][ks] = *(const short8*)((const char*)Bs[nb_] + col * 128 +
                                        (((ks * 4 + q) ^ (col & 7))) * 16);
                }
            if (ct == 3) {   // prefetch A-frags for kt+1 into the shadow slot
                const int nkt2 = kt + 1;
#pragma unroll
                for (int f = 0; f < 4; ++f)
#pragma unroll
                    for (int ks = 0; ks < 2; ++ks) {
                        int row = f * 16 + c;
                        afb[nkt2 & 1][f][ks] = *(const short8*)((const char*)As + row * 512 +
                                     (nkt2 * 8 + (((ks * 4 + q)) ^ (row & 7))) * 16);
                    }
            }
        }
        __builtin_amdgcn_sched_barrier(0);   // pin prefetch reads above the MFMA cluster
#pragma unroll
        for (int f = 0; f < 4; ++f)
#pragma unroll
            for (int nf = 0; nf < 2; ++nf) {
                acc[ct][f][nf] = __builtin_amdgcn_mfma_f32_16x16x32_bf16(
                    afb[kt & 1][f][0], bfb[cb_][nf][0], acc[ct][f][nf], 0, 0, 0);
                acc[ct][f][nf] = __builtin_amdgcn_mfma_f32_16x16x32_bf16(
                    afb[kt & 1][f][1], bfb[cb_][nf][1], acc[ct][f][nf], 0, 0, 0);
            }
    }
    __builtin_amdgcn_sched_barrier(0);   // keep epilogue vmem out of the pipelined window

    // ---- epilogue (once per block): fixed-point pack + top-2 ----
    float ekf[4][2]; unsigned kb[4][2];
#pragma unroll
    for (int ct = 0; ct < 4; ++ct)
#pragma unroll
        for (int nf = 0; nf < 2; ++nf) {
            int col = nbase + ct * 128 + w * 32 + nf * 16 + c;
            ekf[ct][nf] = (esq[col] + 8.0f) * 16384.0f;   // key+8 in quanta
            kb[ct][nf] = (unsigned)col;
        }
    unsigned b1[4][4], b2[4][4];
#pragma unroll
    for (int f = 0; f < 4; ++f)
#pragma unroll
        for (int r = 0; r < 4; ++r) { b1[f][r] = 0xFFFFFFFFu; b2[f][r] = 0xFFFFFFFFu; }
#pragma unroll
    for (int f = 0; f < 4; ++f)
#pragma unroll
        for (int r = 0; r < 4; ++r)
#pragma unroll
            for (int ct = 0; ct < 4; ++ct)
#pragma unroll
                for (int nf = 0; nf < 2; ++nf) {
                    float fx = fmaf(-32768.0f, acc[ct][f][nf][r], ekf[ct][nf]);
                    unsigned p = ((unsigned)fx << 13) | kb[ct][nf];
                    // top-2 insert: b2 = med3(p,b1,b2); b1 = min(b1,p)
                    unsigned nb2;
                    asm("v_med3_u32 %0, %1, %2, %3"
                        : "=v"(nb2) : "v"(p), "v"(b1[f][r]), "v"(b2[f][r]));
                    b2[f][r] = nb2;
                    b1[f][r] = min(b1[f][r], p);
                }
#pragma unroll
    for (int f = 0; f < 4; ++f)
#pragma unroll
        for (int r = 0; r < 4; ++r) {
            unsigned x1 = b1[f][r], x2 = b2[f][r];
#pragma unroll
            for (int sft = 1; sft < 16; sft <<= 1) {
                unsigned o1 = __shfl_xor(x1, sft);
                unsigned o2 = __shfl_xor(x2, sft);
                unsigned mx = max(x1, o1);
                x1 = min(x1, o1);
                x2 = min(min(mx, x2), o2);
            }
            if (c == 0) {
                st[f * 16 + q * 4 + r][w][0] = x1;
                st[f * 16 + q * 4 + r][w][1] = x2;
            }
        }
    __syncthreads();
    if (tid < 64) {
        unsigned a1 = st[tid][0][0], a2 = st[tid][0][1];
#pragma unroll
        for (int ww = 1; ww < 4; ++ww) {
            unsigned p1 = st[tid][ww][0], p2 = st[tid][ww][1];
            unsigned mx = max(a1, p1);
            a1 = min(a1, p1);
            a2 = min(min(mx, a2), p2);
        }
        cand[(size_t)(m0 + tid) * 32 + blockIdx.x * 2 + 0] = a1;
        cand[(size_t)(m0 + tid) * 32 + blockIdx.x * 2 + 1] = a2;
    }
}

// ---------- resolve (numpy-replica fp32 rescore, proven r3/r4) + gather ------
__global__ __launch_bounds__(256) void resolve_gather_kernel(
    const float* __restrict__ z, const float* __restrict__ cb,
    const float* __restrict__ zsq, const float* __restrict__ esq,
    const unsigned* __restrict__ cand, float* __restrict__ out,
    float* __restrict__ partials) {
#pragma clang fp contract(off)
    __shared__ float wls[4];
    int w = threadIdx.x >> 6, l = threadIdx.x & 63;
    int row = blockIdx.x * 4 + w;
    unsigned p = (l < 32) ? cand[(size_t)row * 32 + l] : 0xFFFFFFFFu;
    unsigned m = p;
#pragma unroll
    for (int s = 32; s; s >>= 1) m = min(m, __shfl_xor(m, s));
    bool active = (l < 32) && ((p >> 13) <= (m >> 13) + QWINDOW);
    float dref = FLT_MAX; int k = 0x7FFFFFFF;
    if (active) {
        k = (int)(p & 8191u);
        const float* zr = z + (size_t)row * DDIM;
        const float* er = cb + (size_t)k * DDIM;
        float cacc = 0.f;
#pragma unroll 16   // scheduling only: sequential fma chain order preserved
        for (int d = 0; d < DDIM; ++d)
            cacc = fmaf(zr[d], er[d], cacc);   // BLAS-style sequential-K fma chain
        float s1 = zsq[row] + esq[k];          // numpy: z_sq + e_sq (fp32 round)
        float two = 2.0f * cacc;               // exact
        dref = s1 - two;                       // single fp32 round
    }
#pragma unroll
    for (int s = 32; s; s >>= 1) {
        float od = __shfl_xor(dref, s);
        int ok = __shfl_xor(k, s);
        if (od < dref || (od == dref && ok < k)) { dref = od; k = ok; }
    }
    if (l == 0) out[ZQ_ELEMS + row] = (float)k;
    float ls = 0.f;
#pragma unroll
    for (int t = 0; t < 4; ++t) {
        int d = l + t * 64;
        float e = cb[(size_t)k * DDIM + d];
        float zv = z[(size_t)row * DDIM + d];
        out[(size_t)row * DDIM + d] = zv + (e - zv);  // z_q_st == z_q numerically
        float df = zv - e;
        ls = fmaf(df, df, ls);
    }
#pragma unroll
    for (int s = 32; s; s >>= 1) ls += __shfl_xor(ls, s);
    if (l == 0) wls[w] = ls;
    __syncthreads();
    if (threadIdx.x == 0)
        partials[blockIdx.x] = (wls[0] + wls[1]) + (wls[2] + wls[3]);
}

__global__ __launch_bounds__(256) void final_kernel(const float* __restrict__ partials,
                                                    float* __restrict__ out) {
    __shared__ double wd[4];
    int w = threadIdx.x >> 6, l = threadIdx.x & 63;
    double s = 0.0;
#pragma unroll
    for (int j = 0; j < 16; ++j) s += (double)partials[threadIdx.x + j * 256];
#pragma unroll
    for (int sh = 32; sh; sh >>= 1) s += __shfl_xor(s, sh);
    if (l == 0) wd[w] = s;
    __syncthreads();
    if (threadIdx.x == 0)
        out[ZQ_ELEMS + NROWS] =
            (float)(1.25 * ((wd[0] + wd[1]) + (wd[2] + wd[3])) / (double)ZQ_ELEMS);
}

extern "C" void kernel_launch(void* const* d_in, const int* in_sizes, int n_in,
                              void* d_out, int out_size, void* d_ws, size_t ws_size,
                              hipStream_t stream) {
    const float* z = (const float*)d_in[0];
    const float* cb = (const float*)d_in[1];
    float* out = (float*)d_out;
    char* ws = (char*)d_ws;
    float* esq = (float*)(ws + WS_ESQ_OFF);
    float* zsq = (float*)(ws + WS_ZSQ_OFF);
    unsigned* cand = (unsigned*)(ws + WS_CAND_OFF);
    float* partials = (float*)(ws + WS_PART_OFF);
    // bf16 scratch inside d_out (12 MB < 16.8 MB); overwritten by outputs later
    unsigned short* z16 = (unsigned short*)d_out;
    unsigned short* cb16 = z16 + (size_t)NROWS * DDIM;

    prep_kernel<<<dim3((KCB + NROWS) / 64), 256, 0, stream>>>(z, cb, z16, cb16, esq, zsq);
    gemm_filter_kernel<<<dim3(16, NROWS / 64), 256, 0, stream>>>(z16, cb16, esq, cand);
    resolve_gather_kernel<<<dim3(NROWS / 4), 256, 0, stream>>>(z, cb, zsq, esq, cand, out, partials);
    final_kernel<<<1, 256, 0, stream>>>(partials, out);
}

// Round 6
// 240.318 us; speedup vs baseline: 1.2327x; 1.0202x over previous
//
#include <hip/hip_runtime.h>
#include <hip/hip_bf16.h>
#include <float.h>

// Problem constants (B,H,W,D,K) = (16,32,32,256,8192)
#define NROWS 16384
#define DDIM  256
#define KCB   8192
#define ZQ_ELEMS 4194304

// ws layout (~2.2 MB; r0-proven)
#define WS_ESQ_OFF   0                      // float[8192]
#define WS_ZSQ_OFF   32768                  // float[16384]
#define WS_CAND_OFF  98304                  // u32[16384*32] = 2 MB
#define WS_PART_OFF  (98304 + 2097152)      // float[4096]

#define QWINDOW 410   // rescore window: 0.025 in 1/16384 fixed-point quanta

typedef __attribute__((ext_vector_type(8))) short short8;
typedef __attribute__((ext_vector_type(4))) float floatx4;

__device__ __forceinline__ unsigned short bf16_rn(float f) {
    unsigned u = __float_as_uint(f);
    return (unsigned short)((u + 0x7FFFu + ((u >> 16) & 1u)) >> 16);
}

// async global->LDS DMA, 16 B per lane; LDS dest = wave-uniform base + lane*16
__device__ __forceinline__ void gload_lds16(const void* g, void* l) {
    __builtin_amdgcn_global_load_lds(
        (const __attribute__((address_space(1))) void*)(uintptr_t)g,
        (__attribute__((address_space(3))) void*)(unsigned)(uintptr_t)l, 16, 0, 0);
}

// ---------- prep: bf16 convert + numpy-pairwise sumsq (bit-exact, proven r3) ----
__global__ __launch_bounds__(256) void prep_kernel(
    const float* __restrict__ z, const float* __restrict__ cb,
    unsigned short* __restrict__ z16, unsigned short* __restrict__ cb16,
    float* __restrict__ esq, float* __restrict__ zsq) {
#pragma clang fp contract(off)
    int tid = threadIdx.x;
    int rowb = tid >> 2, sub = tid & 3;
    int b = sub >> 1, jq = sub & 1;
    int row = blockIdx.x * 64 + rowb;
    const float* src; unsigned short* dst; float* o;
    if (row < KCB) { src = cb + (size_t)row * DDIM; dst = cb16 + (size_t)row * DDIM; o = esq + row; }
    else { int r = row - KCB; src = z + (size_t)r * DDIM; dst = z16 + (size_t)r * DDIM; o = zsq + r; }
    float r0 = 0.f, r1 = 0.f, r2 = 0.f, r3 = 0.f;
#pragma unroll   // scheduling only: 16 independent float4 loads pipelined; fp order unchanged
    for (int t = 0; t < 16; ++t) {
        int off = b * 128 + t * 8 + jq * 4;
        float4 v = *(const float4*)(src + off);
        float q0 = v.x * v.x, q1 = v.y * v.y, q2 = v.z * v.z, q3 = v.w * v.w;
        r0 = r0 + q0; r1 = r1 + q1; r2 = r2 + q2; r3 = r3 + q3;
        ushort4 w;
        w.x = bf16_rn(v.x); w.y = bf16_rn(v.y); w.z = bf16_rn(v.z); w.w = bf16_rn(v.w);
        *(ushort4*)(dst + off) = w;
    }
    float s = (r0 + r1) + (r2 + r3);
    s = s + __shfl_xor(s, 1);   // jq pair
    s = s + __shfl_xor(s, 2);   // block pair
    if (sub == 0) *o = s;
}

// ---------- bf16 MFMA filter: block = 64 z-rows x 512 cols, 8 WAVES ----------
// R0/R4/R5 all land at ~116us with identical MfmaUtil ~25% at 2 waves/SIMD:
// the schedule is not the constraint — WAVE COUNT is (acc[4][4][2]=128 AGPR
// + 124 VGPR = register-limited to 2 waves/SIMD; 66KB LDS also caps 2 blocks).
// THIS version: 512 threads, wave (wm,wn) in a 2x4 grid owns 32 rows x 128
// cols -> acc[4ct][2f][2nf] = 64 AGPR, per-wave epilogue halved, total regs
// ~128 -> __launch_bounds__(512,4) gives 4 waves/SIMD (16 waves/CU), 2x TLP
// at IDENTICAL per-CU work, LDS, DMA, and block count. Schedule = R0-proven
// per-step barrier loop (R4 showed barrier == counted-wait).
__global__ __launch_bounds__(512, 4) void gemm_filter_kernel(
    const unsigned short* __restrict__ z16, const unsigned short* __restrict__ cb16,
    const float* __restrict__ esq, unsigned* __restrict__ cand) {
    __shared__ unsigned short As[64 * 256];     // 32 KB
    __shared__ unsigned short Bs[2][128 * 64];  // 2 x 16 KB
    __shared__ unsigned st[64][4][2];           // 2 KB cross-wave top-2 merge

    const int tid = threadIdx.x;
    const int w = tid >> 6, lane = tid & 63;
    const int wm = w >> 2, wn = w & 3;          // wave tile: rows wm*32+, cols wn*32 per chunk
    const int c = lane & 15, q = lane >> 4;
    const int m0 = blockIdx.y * 64;
    const int nbase = blockIdx.x * 512;

    // prologue: A tile (4 DMA ops/wave) + B chunk 0 (2 ops/wave)
#pragma unroll
    for (int p = 0; p < 4; ++p) {
        int s = (w * 4 + p) * 64 + lane;
        int row = s >> 5, jp = s & 31;
        int j = (jp & 24) | ((jp & 7) ^ (row & 7));   // source-addr XOR swizzle
        gload_lds16(z16 + (size_t)(m0 + row) * 256 + j * 8,
                    (char*)As + (w * 4 + p) * 1024);
    }
#pragma unroll
    for (int p = 0; p < 2; ++p) {
        int s = (w * 2 + p) * 64 + lane;
        int col = s >> 3, jp = s & 7;
        int j = jp ^ (col & 7);
        gload_lds16(cb16 + (size_t)(nbase + col) * 256 + j * 8,
                    (char*)Bs[0] + (w * 2 + p) * 1024);
    }
    __syncthreads();

    floatx4 acc[4][2][2];   // [ct][f][nf] — 64 regs
#pragma unroll
    for (int ct = 0; ct < 4; ++ct)
#pragma unroll
        for (int f = 0; f < 2; ++f)
#pragma unroll
            for (int nf = 0; nf < 2; ++nf) acc[ct][f][nf] = (floatx4){0.f, 0.f, 0.f, 0.f};

    short8 af[2][2];   // [f][ks] for current kt

#pragma unroll
    for (int s5 = 0; s5 < 16; ++s5) {
        const int kt = s5 >> 2, ct = s5 & 3, cur = s5 & 1;
        if (s5 < 15) {   // prefetch next cb chunk into other buffer
            const int nkt = (s5 + 1) >> 2, nct = (s5 + 1) & 3;
#pragma unroll
            for (int p = 0; p < 2; ++p) {
                int s = (w * 2 + p) * 64 + lane;
                int col = s >> 3, jp = s & 7;
                int j = jp ^ (col & 7);
                gload_lds16(cb16 + (size_t)(nbase + nct * 128 + col) * 256 + nkt * 64 + j * 8,
                            (char*)Bs[cur ^ 1] + (w * 2 + p) * 1024);
            }
        }
        if (ct == 0) {   // A-frags for this kt (reused across 4 ct)
#pragma unroll
            for (int f = 0; f < 2; ++f)
#pragma unroll
                for (int ks = 0; ks < 2; ++ks) {
                    int row = wm * 32 + f * 16 + c;
                    af[f][ks] = *(const short8*)((const char*)As + row * 512 +
                                 (kt * 8 + (((ks * 4 + q)) ^ (row & 7))) * 16);
                }
        }
        short8 bf[2][2];
#pragma unroll
        for (int nf = 0; nf < 2; ++nf)
#pragma unroll
            for (int ks = 0; ks < 2; ++ks) {
                int col = wn * 32 + nf * 16 + c;
                bf[nf][ks] = *(const short8*)((const char*)Bs[cur] + col * 128 +
                              (((ks * 4 + q) ^ (col & 7))) * 16);
            }
#pragma unroll
        for (int f = 0; f < 2; ++f)
#pragma unroll
            for (int nf = 0; nf < 2; ++nf) {
                acc[ct][f][nf] = __builtin_amdgcn_mfma_f32_16x16x32_bf16(
                    af[f][0], bf[nf][0], acc[ct][f][nf], 0, 0, 0);
                acc[ct][f][nf] = __builtin_amdgcn_mfma_f32_16x16x32_bf16(
                    af[f][1], bf[nf][1], acc[ct][f][nf], 0, 0, 0);
            }
        __syncthreads();   // buf cur consumed; next chunk's DMA drained here
    }

    // ---- epilogue (once per block): fixed-point pack + top-2 ----
    float ekf[4][2]; unsigned kb[4][2];
#pragma unroll
    for (int ct = 0; ct < 4; ++ct)
#pragma unroll
        for (int nf = 0; nf < 2; ++nf) {
            int col = nbase + ct * 128 + wn * 32 + nf * 16 + c;
            ekf[ct][nf] = (esq[col] + 8.0f) * 16384.0f;   // key+8 in quanta
            kb[ct][nf] = (unsigned)col;
        }
    unsigned b1[2][4], b2[2][4];
#pragma unroll
    for (int f = 0; f < 2; ++f)
#pragma unroll
        for (int r = 0; r < 4; ++r) { b1[f][r] = 0xFFFFFFFFu; b2[f][r] = 0xFFFFFFFFu; }
#pragma unroll
    for (int f = 0; f < 2; ++f)
#pragma unroll
        for (int r = 0; r < 4; ++r)
#pragma unroll
            for (int ct = 0; ct < 4; ++ct)
#pragma unroll
                for (int nf = 0; nf < 2; ++nf) {
                    float fx = fmaf(-32768.0f, acc[ct][f][nf][r], ekf[ct][nf]);
                    unsigned p = ((unsigned)fx << 13) | kb[ct][nf];
                    // top-2 insert: b2 = med3(p,b1,b2); b1 = min(b1,p)
                    unsigned nb2;
                    asm("v_med3_u32 %0, %1, %2, %3"
                        : "=v"(nb2) : "v"(p), "v"(b1[f][r]), "v"(b2[f][r]));
                    b2[f][r] = nb2;
                    b1[f][r] = min(b1[f][r], p);
                }
#pragma unroll
    for (int f = 0; f < 2; ++f)
#pragma unroll
        for (int r = 0; r < 4; ++r) {
            unsigned x1 = b1[f][r], x2 = b2[f][r];
#pragma unroll
            for (int sft = 1; sft < 16; sft <<= 1) {
                unsigned o1 = __shfl_xor(x1, sft);
                unsigned o2 = __shfl_xor(x2, sft);
                unsigned mx = max(x1, o1);
                x1 = min(x1, o1);
                x2 = min(min(mx, x2), o2);
            }
            if (c == 0) {
                st[wm * 32 + f * 16 + q * 4 + r][wn][0] = x1;
                st[wm * 32 + f * 16 + q * 4 + r][wn][1] = x2;
            }
        }
    __syncthreads();
    if (tid < 64) {
        unsigned a1 = st[tid][0][0], a2 = st[tid][0][1];
#pragma unroll
        for (int ww = 1; ww < 4; ++ww) {
            unsigned p1 = st[tid][ww][0], p2 = st[tid][ww][1];
            unsigned mx = max(a1, p1);
            a1 = min(a1, p1);
            a2 = min(min(mx, a2), p2);
        }
        cand[(size_t)(m0 + tid) * 32 + blockIdx.x * 2 + 0] = a1;
        cand[(size_t)(m0 + tid) * 32 + blockIdx.x * 2 + 1] = a2;
    }
}

// ---------- resolve (numpy-replica fp32 rescore, proven r3/r4) + gather ------
__global__ __launch_bounds__(256) void resolve_gather_kernel(
    const float* __restrict__ z, const float* __restrict__ cb,
    const float* __restrict__ zsq, const float* __restrict__ esq,
    const unsigned* __restrict__ cand, float* __restrict__ out,
    float* __restrict__ partials) {
#pragma clang fp contract(off)
    __shared__ float wls[4];
    int w = threadIdx.x >> 6, l = threadIdx.x & 63;
    int row = blockIdx.x * 4 + w;
    unsigned p = (l < 32) ? cand[(size_t)row * 32 + l] : 0xFFFFFFFFu;
    unsigned m = p;
#pragma unroll
    for (int s = 32; s; s >>= 1) m = min(m, __shfl_xor(m, s));
    bool active = (l < 32) && ((p >> 13) <= (m >> 13) + QWINDOW);
    float dref = FLT_MAX; int k = 0x7FFFFFFF;
    if (active) {
        k = (int)(p & 8191u);
        const float* zr = z + (size_t)row * DDIM;
        const float* er = cb + (size_t)k * DDIM;
        float cacc = 0.f;
#pragma unroll 16   // scheduling only: sequential fma chain order preserved
        for (int d = 0; d < DDIM; ++d)
            cacc = fmaf(zr[d], er[d], cacc);   // BLAS-style sequential-K fma chain
        float s1 = zsq[row] + esq[k];          // numpy: z_sq + e_sq (fp32 round)
        float two = 2.0f * cacc;               // exact
        dref = s1 - two;                       // single fp32 round
    }
#pragma unroll
    for (int s = 32; s; s >>= 1) {
        float od = __shfl_xor(dref, s);
        int ok = __shfl_xor(k, s);
        if (od < dref || (od == dref && ok < k)) { dref = od; k = ok; }
    }
    if (l == 0) out[ZQ_ELEMS + row] = (float)k;
    float ls = 0.f;
#pragma unroll
    for (int t = 0; t < 4; ++t) {
        int d = l + t * 64;
        float e = cb[(size_t)k * DDIM + d];
        float zv = z[(size_t)row * DDIM + d];
        out[(size_t)row * DDIM + d] = zv + (e - zv);  // z_q_st == z_q numerically
        float df = zv - e;
        ls = fmaf(df, df, ls);
    }
#pragma unroll
    for (int s = 32; s; s >>= 1) ls += __shfl_xor(ls, s);
    if (l == 0) wls[w] = ls;
    __syncthreads();
    if (threadIdx.x == 0)
        partials[blockIdx.x] = (wls[0] + wls[1]) + (wls[2] + wls[3]);
}

__global__ __launch_bounds__(256) void final_kernel(const float* __restrict__ partials,
                                                    float* __restrict__ out) {
    __shared__ double wd[4];
    int w = threadIdx.x >> 6, l = threadIdx.x & 63;
    double s = 0.0;
#pragma unroll
    for (int j = 0; j < 16; ++j) s += (double)partials[threadIdx.x + j * 256];
#pragma unroll
    for (int sh = 32; sh; sh >>= 1) s += __shfl_xor(s, sh);
    if (l == 0) wd[w] = s;
    __syncthreads();
    if (threadIdx.x == 0)
        out[ZQ_ELEMS + NROWS] =
            (float)(1.25 * ((wd[0] + wd[1]) + (wd[2] + wd[3])) / (double)ZQ_ELEMS);
}

extern "C" void kernel_launch(void* const* d_in, const int* in_sizes, int n_in,
                              void* d_out, int out_size, void* d_ws, size_t ws_size,
                              hipStream_t stream) {
    const float* z = (const float*)d_in[0];
    const float* cb = (const float*)d_in[1];
    float* out = (float*)d_out;
    char* ws = (char*)d_ws;
    float* esq = (float*)(ws + WS_ESQ_OFF);
    float* zsq = (float*)(ws + WS_ZSQ_OFF);
    unsigned* cand = (unsigned*)(ws + WS_CAND_OFF);
    float* partials = (float*)(ws + WS_PART_OFF);
    // bf16 scratch inside d_out (12 MB < 16.8 MB); overwritten by outputs later
    unsigned short* z16 = (unsigned short*)d_out;
    unsigned short* cb16 = z16 + (size_t)NROWS * DDIM;

    prep_kernel<<<dim3((KCB + NROWS) / 64), 256, 0, stream>>>(z, cb, z16, cb16, esq, zsq);
    gemm_filter_kernel<<<dim3(16, NROWS / 64), 512, 0, stream>>>(z16, cb16, esq, cand);
    resolve_gather_kernel<<<dim3(NROWS / 4), 256, 0, stream>>>(z, cb, zsq, esq, cand, out, partials);
    final_kernel<<<1, 256, 0, stream>>>(partials, out);
}